// Round 10
// baseline (5331488.281 us; speedup 1.0000x reference)
//
#include <hip/hip_runtime.h>
#include <hip/hip_bf16.h>

#define B_SZ   2048
#define F_IN   1024
#define R_EMB  1024
#define F_OUT  1024
#define F_MID  2048
#define NNZ_E  65536
#define NNZ_W  131072
#define NNZ_B  512
#define NBLK   512

typedef __bf16 bf16x8 __attribute__((ext_vector_type(8)));
typedef float  f32x4  __attribute__((ext_vector_type(4)));

__device__ inline void gload16(const void* g, void* l) {
    __builtin_amdgcn_global_load_lds(
        (const __attribute__((address_space(1))) void*)g,
        (__attribute__((address_space(3))) void*)l, 16, 0, 0);
}

__device__ inline ushort f2bf(float v) {
    __hip_bfloat16 h = __float2bfloat16(v);
    return *reinterpret_cast<ushort*>(&h);
}

// Grid barrier for a 512-block grid (2 blocks/CU = HALF device capacity;
// launch_bounds(256,2) caps VGPR at 256 so co-residency is structural).
// Bounded spin: if co-residency is ever violated, we break out after ~0.25 s
// instead of hanging the harness (R9 lesson: exact-capacity spin = deadlock).
// Release side: all threads __threadfence() (device-scope L2 writeback).
// Acquire side: fence again after the barrier so plain loads see remote stores.
__device__ __forceinline__ void gridbar(int* cnt, int* gen, int next) {
    __threadfence();
    __syncthreads();
    if (threadIdx.x == 0) {
        int prev = __hip_atomic_fetch_add(cnt, 1, __ATOMIC_ACQ_REL,
                                          __HIP_MEMORY_SCOPE_AGENT);
        if (prev == NBLK - 1) {
            __hip_atomic_store(cnt, 0, __ATOMIC_RELAXED, __HIP_MEMORY_SCOPE_AGENT);
            __hip_atomic_store(gen, next, __ATOMIC_RELEASE, __HIP_MEMORY_SCOPE_AGENT);
        } else {
            int iters = 0;
            while (__hip_atomic_load(gen, __ATOMIC_ACQUIRE,
                                     __HIP_MEMORY_SCOPE_AGENT) < next &&
                   ++iters < (1 << 21))
                __builtin_amdgcn_s_sleep(2);
        }
    }
    __syncthreads();
    __threadfence();
}

// R6 64x64x64 GEMM core (proven best: 2-phase dbuf, XOR chunk-swizzle,
// 4 waves of 32x32 wave tiles, 16x16x32 MFMA).
//   mode 0: h = relu(A @ Bm^T)      -> bf16 hOut (x2 right half)
//   mode 1: out = A @ Bm^T + bias   -> f32
//   mode 2: out += A @ Bm^T         -> f32 RMW
__device__ __forceinline__ void gemm64(
    ushort (*lds)[2][64 * 64],          // [2 buf][A|B][4096]
    int mode, int m0, int n0,
    const ushort* __restrict__ A, const ushort* __restrict__ Bm, int ldb,
    const float* __restrict__ biasd, float* __restrict__ out,
    ushort* __restrict__ hOut)
{
    constexpr int BK = 64, NT = 16;
    const int tid = threadIdx.x;
    const int w = tid >> 6, l = tid & 63;
    const int wr = w >> 1, wc = w & 1;
    const int la = l & 15;
    const int srow = w * 8 + (l >> 3);
    const int ldst = w * 512 + l * 8;

    f32x4 acc[2][2] = {};

    #define STAGE(buf, k0)                                                      \
        _Pragma("unroll")                                                       \
        for (int i = 0; i < 2; ++i) {                                           \
            int row = i * 32 + srow;                                            \
            int scol = (k0) + ((((l & 7) ^ (row & 7))) << 3);                   \
            gload16(A  + (size_t)(m0 + row) * F_MID + scol,                     \
                    &lds[buf][0][i * 2048 + ldst]);                             \
            gload16(Bm + (size_t)(n0 + row) * ldb + scol,                       \
                    &lds[buf][1][i * 2048 + ldst]);                             \
        }

    STAGE(0, 0);
    __syncthreads();

    for (int t = 0; t < NT; ++t) {
        const int cur = t & 1;
        if (t + 1 < NT) STAGE(cur ^ 1, (t + 1) * BK);

        const ushort* sA = &lds[cur][0][0];
        const ushort* sB = &lds[cur][1][0];
        #pragma unroll
        for (int ks = 0; ks < 2; ++ks) {
            const int k8 = ks * 4 + (l >> 4);
            bf16x8 af[2], bg[2];
            #pragma unroll
            for (int m = 0; m < 2; ++m) {
                int row = wr * 32 + m * 16 + la;
                af[m] = *(const bf16x8*)(sA + row * BK + ((k8 ^ (row & 7)) << 3));
            }
            #pragma unroll
            for (int n = 0; n < 2; ++n) {
                int row = wc * 32 + n * 16 + la;
                bg[n] = *(const bf16x8*)(sB + row * BK + ((k8 ^ (row & 7)) << 3));
            }
            #pragma unroll
            for (int m = 0; m < 2; ++m)
                #pragma unroll
                for (int n = 0; n < 2; ++n)
                    acc[m][n] = __builtin_amdgcn_mfma_f32_16x16x32_bf16(
                        af[m], bg[n], acc[m][n], 0, 0, 0);
        }
        __syncthreads();
    }
    #undef STAGE

    // C/D layout (verified m89/m91): col = lane&15, row = (lane>>4)*4 + reg.
    const int lr = (l >> 4) * 4;
    #pragma unroll
    for (int m = 0; m < 2; ++m) {
        #pragma unroll
        for (int n = 0; n < 2; ++n) {
            const int col = n0 + wc * 32 + n * 16 + la;
            if (mode == 0) {
                #pragma unroll
                for (int j = 0; j < 4; ++j) {
                    int row = m0 + wr * 32 + m * 16 + lr + j;
                    hOut[(size_t)row * F_MID + col] = f2bf(fmaxf(acc[m][n][j], 0.f));
                }
            } else if (mode == 1) {
                const float bv = biasd[col];
                #pragma unroll
                for (int j = 0; j < 4; ++j) {
                    int row = m0 + wr * 32 + m * 16 + lr + j;
                    out[(size_t)row * F_OUT + col] = acc[m][n][j] + bv;
                }
            } else {
                #pragma unroll
                for (int j = 0; j < 4; ++j) {
                    int row = m0 + wr * 32 + m * 16 + lr + j;
                    out[(size_t)row * F_OUT + col] += acc[m][n][j];
                }
            }
        }
    }
}

// Single persistent kernel: zero -> scatter -> cvt -> GEMM A -> GEMM B,
// separated by in-kernel grid barriers (no launch gaps, no dispatch ramps).
__global__ __launch_bounds__(256, 2)
void k_mega(const float* __restrict__ x,
            const int* __restrict__ er, const int* __restrict__ ec,
            const float* __restrict__ ev,
            const int* __restrict__ wr_, const int* __restrict__ wc_,
            const float* __restrict__ wv,
            const int* __restrict__ bi, const float* __restrict__ bv,
            float* __restrict__ out,
            ushort* __restrict__ x2,   float* __restrict__ Wf,
            float* __restrict__ Ef,    float* __restrict__ biasd,
            ushort* __restrict__ Ebf,  ushort* __restrict__ Wbf,
            int* __restrict__ bar)
{
    __shared__ ushort lds[2][2][64 * 64];   // 32 KB
    int* cnt = bar;
    int* gen = bar + 1;
    const int blk = blockIdx.x, tid = threadIdx.x;
    const int gidx = blk * 256 + tid;       // 0 .. 131071

    // ---- phase 0: zero Wf | Ef | bias (contiguous 12 MB + 4 KB = 786688 f4)
    {
        float4* zb = (float4*)Wf;
        float4 z = make_float4(0.f, 0.f, 0.f, 0.f);
        for (int i = gidx; i < 786688; i += NBLK * 256) zb[i] = z;
    }
    gridbar(cnt, gen, 1);

    // ---- phase 1: scatter-add (device-scope atomics -> XCD-coherent)
    for (int i = gidx; i < NNZ_E + NNZ_W + NNZ_B; i += NBLK * 256) {
        if (i < NNZ_E) {
            atomicAdd(&Ef[(size_t)er[i] * F_IN + ec[i]], ev[i]);
        } else if (i < NNZ_E + NNZ_W) {
            int j = i - NNZ_E;
            atomicAdd(&Wf[(size_t)wr_[j] * F_MID + wc_[j]], wv[j]);
        } else {
            int j = i - (NNZ_E + NNZ_W);
            atomicAdd(&biasd[bi[j]], bv[j]);
        }
    }
    gridbar(cnt, gen, 2);

    // ---- phase 2: f32 -> bf16 (x into x2 left half; Ef->Ebf; Wf->Wbf)
    for (int i = gidx; i < 1310720; i += NBLK * 256) {
        if (i < 524288) {
            float4 v = ((const float4*)x)[i];
            int row = i >> 8, c4 = i & 255;
            ((ushort4*)x2)[(size_t)row * (F_MID / 4) + c4] =
                make_ushort4(f2bf(v.x), f2bf(v.y), f2bf(v.z), f2bf(v.w));
        } else if (i < 786432) {
            int j = i - 524288;
            float4 v = ((const float4*)Ef)[j];
            ((ushort4*)Ebf)[j] = make_ushort4(f2bf(v.x), f2bf(v.y), f2bf(v.z), f2bf(v.w));
        } else {
            int j = i - 786432;
            float4 v = ((const float4*)Wf)[j];
            ((ushort4*)Wbf)[j] = make_ushort4(f2bf(v.x), f2bf(v.y), f2bf(v.z), f2bf(v.w));
        }
    }
    gridbar(cnt, gen, 3);

    // ---- phase 3: GEMM A  {h = relu(x @ E^T)}  then  {out = x @ W_L^T + bias}
    //      2 sequential tiles/block.  All-h-first: all 512 blocks share Ebf in
    //      L2 during sub-round 1, Wbf during sub-round 2.
    {
        int tt = blk;                               // by 0..15 -> mode 0
        gemm64(lds, 0, (tt & 31) * 64, (tt >> 5) * 64,
               x2, Ebf, F_IN, biasd, out, x2 + F_IN);
        tt = blk + 512;                             // by 16..31 -> mode 1
        gemm64(lds, 1, (tt & 31) * 64, ((tt >> 5) - 16) * 64,
               x2, Wbf, F_MID, biasd, out, x2 + F_IN);
    }
    gridbar(cnt, gen, 4);

    // ---- phase 4: GEMM B  out += h @ W_R^T   (one tile per block)
    gemm64(lds, 2, (blk & 31) * 64, (blk >> 5) * 64,
           x2 + F_IN, Wbf + F_IN, F_MID, biasd, out, x2 + F_IN);
}

extern "C" void kernel_launch(void* const* d_in, const int* in_sizes, int n_in,
                              void* d_out, int out_size, void* d_ws, size_t ws_size,
                              hipStream_t stream) {
    const float* x          = (const float*)d_in[0];
    const int*   embed_rows = (const int*)  d_in[1];
    const int*   embed_cols = (const int*)  d_in[2];
    const float* embed_vals = (const float*)d_in[3];
    const int*   w_rows     = (const int*)  d_in[4];
    const int*   w_cols     = (const int*)  d_in[5];
    const float* w_vals     = (const float*)d_in[6];
    const int*   bias_idx   = (const int*)  d_in[7];
    const float* bias_vals  = (const float*)d_in[8];
    float* out = (float*)d_out;

    // Workspace layout (~26 MB + 8 B barrier state):
    //   [0, 8M)          x2 bf16 [2048][2048]  (left = x, right = relu h)
    //   [8M, 16M)        W_f32 [1024][2048]
    //   [16M, 20M)       E_f32 [1024][1024]
    //   [20M, 20M+4K)    bias f32 [1024]
    //   [20M+4K, 22M+4K) E_bf16 [1024][1024]
    //   [22M+4K, 26M+4K) W_bf16 [1024][2048]
    //   [26M, 26M+8)     grid-barrier {cnt, gen}
    char* ws = (char*)d_ws;
    ushort* x2    = (ushort*)ws;
    float*  Wf    = (float*)(ws + (8u << 20));
    float*  Ef    = (float*)(ws + (16u << 20));
    float*  biasd = (float*)(ws + (20u << 20));
    ushort* Ebf   = (ushort*)(ws + (20u << 20) + 4096);
    ushort* Wbf   = (ushort*)(ws + (22u << 20) + 4096);
    int*    bar   = (int*)(ws + (26u << 20));

    // Re-zero barrier state every call (graph-replay deterministic).
    hipMemsetAsync(bar, 0, 8, stream);

    k_mega<<<NBLK, 256, 0, stream>>>(x,
                                     embed_rows, embed_cols, embed_vals,
                                     w_rows, w_cols, w_vals,
                                     bias_idx, bias_vals,
                                     out, x2, Wf, Ef, biasd, Ebf, Wbf, bar);
}

// Round 11
// 55.007 us; speedup vs baseline: 96924.1848x; 96924.1848x over previous
//
#include <hip/hip_runtime.h>
#include <hip/hip_bf16.h>

#define B_SZ   2048
#define F_IN   1024
#define R_EMB  1024
#define F_OUT  1024
#define F_MID  2048
#define NNZ_E  65536
#define NNZ_W  131072
#define NNZ_B  512

typedef __bf16 bf16x8 __attribute__((ext_vector_type(8)));
typedef float  f32x4  __attribute__((ext_vector_type(4)));

__device__ inline void gload16(const void* g, void* l) {
    __builtin_amdgcn_global_load_lds(
        (const __attribute__((address_space(1))) void*)g,
        (__attribute__((address_space(3))) void*)l, 16, 0, 0);
}

__device__ inline ushort f2bf(float v) {
    __hip_bfloat16 h = __float2bfloat16(v);
    return *reinterpret_cast<ushort*>(&h);
}

__global__ void k_zero4(float4* __restrict__ p, int n) {
    int i = blockIdx.x * blockDim.x + threadIdx.x;
    if (i < n) p[i] = make_float4(0.f, 0.f, 0.f, 0.f);
}

// One launch for all three scatter-adds (blocks partitioned by range).
__global__ void k_scatter_fused(const int* __restrict__ er, const int* __restrict__ ec,
                                const float* __restrict__ ev,
                                const int* __restrict__ wr_, const int* __restrict__ wc_,
                                const float* __restrict__ wv,
                                const int* __restrict__ bi, const float* __restrict__ bv,
                                float* __restrict__ Ef, float* __restrict__ Wf,
                                float* __restrict__ biasd) {
    int b = blockIdx.x, t = threadIdx.x;
    if (b < NNZ_E / 256) {
        int i = b * 256 + t;
        atomicAdd(&Ef[(size_t)er[i] * F_IN + ec[i]], ev[i]);
    } else if (b < NNZ_E / 256 + NNZ_W / 256) {
        int i = (b - NNZ_E / 256) * 256 + t;
        atomicAdd(&Wf[(size_t)wr_[i] * F_MID + wc_[i]], wv[i]);
    } else {
        int i = t;
        atomicAdd(&biasd[bi[i]], bv[i]);
        i += 256;
        atomicAdd(&biasd[bi[i]], bv[i]);
    }
}

// One launch for all three f32->bf16 conversions.
__global__ void k_cvt_fused(const float4* __restrict__ x, ushort* __restrict__ x2,
                            const float4* __restrict__ Ef, ushort* __restrict__ Ebf,
                            const float4* __restrict__ Wf, ushort* __restrict__ Wbf) {
    int b = blockIdx.x, t = threadIdx.x;
    if (b < 2048) {
        int i = b * 256 + t;                 // float4 index into x
        int row = i >> 8, c4 = i & 255;      // 256 float4 per row of 1024
        float4 v = x[i];
        ((ushort4*)x2)[(size_t)row * (F_MID / 4) + c4] =
            make_ushort4(f2bf(v.x), f2bf(v.y), f2bf(v.z), f2bf(v.w));
    } else if (b < 3072) {
        int i = (b - 2048) * 256 + t;
        float4 v = Ef[i];
        ((ushort4*)Ebf)[i] = make_ushort4(f2bf(v.x), f2bf(v.y), f2bf(v.z), f2bf(v.w));
    } else {
        int i = (b - 3072) * 256 + t;
        float4 v = Wf[i];
        ((ushort4*)Wbf)[i] = make_ushort4(f2bf(v.x), f2bf(v.y), f2bf(v.z), f2bf(v.w));
    }
}

// GEMM-A' (dual-B fusion): one block per (m0,n0) stages its A-tile ONCE and
// computes BOTH  h[m0,n0] = relu(x @ E^T)  and  out[m0,n0] = x @ W_L^T + bias.
// R6 core otherwise: 64x64x64 tiles, 2-phase dbuf, XOR chunk-swizzle,
// 4 waves of 32x32 wave tiles, 16x16x32 MFMA.  16 MFMA / 12 ds_reads / K-step.
// Bijective XCD chunk-swizzle: XCD k owns m-panels [4k, 4k+4) x all 16 n.
__global__ __launch_bounds__(256)
void k_gemmA(const ushort* __restrict__ x2,   // [2048][2048] bf16 (left half = x)
             const ushort* __restrict__ Ebf,  // [1024][1024] bf16
             const ushort* __restrict__ Wbf,  // [1024][2048] bf16
             const float* __restrict__ biasd, // [1024]
             float* __restrict__ out,         // [2048][1024] f32
             ushort* __restrict__ hOut)       // = x2 + F_IN
{
    constexpr int BK = 64, NT = 16;
    __shared__ ushort lds[2][3][64 * 64];     // [buf][A|BE|BW], 48 KB
    const int tid = threadIdx.x;
    const int w = tid >> 6, l = tid & 63;
    const int wr = w >> 1, wc = w & 1;
    const int la = l & 15;

    const int blk = blockIdx.x;               // 512 blocks
    const int sw  = (blk & 7) * 64 + (blk >> 3);   // XCD chunk swizzle (512=8*64)
    const int m0  = (sw >> 4) * 64;
    const int n0  = (sw & 15) * 64;

    const int srow = w * 8 + (l >> 3);
    const int ldst = w * 512 + l * 8;

    f32x4 accE[2][2] = {}, accW[2][2] = {};

    #define STAGE(buf, k0)                                                      \
        _Pragma("unroll")                                                       \
        for (int i = 0; i < 2; ++i) {                                           \
            int row = i * 32 + srow;                                            \
            int scol = (k0) + ((((l & 7) ^ (row & 7))) << 3);                   \
            gload16(x2  + (size_t)(m0 + row) * F_MID + scol,                    \
                    &lds[buf][0][i * 2048 + ldst]);                             \
            gload16(Ebf + (size_t)(n0 + row) * F_IN + scol,                     \
                    &lds[buf][1][i * 2048 + ldst]);                             \
            gload16(Wbf + (size_t)(n0 + row) * F_MID + scol,                    \
                    &lds[buf][2][i * 2048 + ldst]);                             \
        }

    STAGE(0, 0);
    __syncthreads();

    for (int t = 0; t < NT; ++t) {
        const int cur = t & 1;
        if (t + 1 < NT) STAGE(cur ^ 1, (t + 1) * BK);

        const ushort* sA  = &lds[cur][0][0];
        const ushort* sBE = &lds[cur][1][0];
        const ushort* sBW = &lds[cur][2][0];
        #pragma unroll
        for (int ks = 0; ks < 2; ++ks) {
            const int k8 = ks * 4 + (l >> 4);
            bf16x8 af[2], be[2], bw[2];
            #pragma unroll
            for (int m = 0; m < 2; ++m) {
                int row = wr * 32 + m * 16 + la;
                af[m] = *(const bf16x8*)(sA + row * BK + ((k8 ^ (row & 7)) << 3));
            }
            #pragma unroll
            for (int n = 0; n < 2; ++n) {
                int row = wc * 32 + n * 16 + la;
                be[n] = *(const bf16x8*)(sBE + row * BK + ((k8 ^ (row & 7)) << 3));
                bw[n] = *(const bf16x8*)(sBW + row * BK + ((k8 ^ (row & 7)) << 3));
            }
            #pragma unroll
            for (int m = 0; m < 2; ++m)
                #pragma unroll
                for (int n = 0; n < 2; ++n) {
                    accE[m][n] = __builtin_amdgcn_mfma_f32_16x16x32_bf16(
                        af[m], be[n], accE[m][n], 0, 0, 0);
                    accW[m][n] = __builtin_amdgcn_mfma_f32_16x16x32_bf16(
                        af[m], bw[n], accW[m][n], 0, 0, 0);
                }
        }
        __syncthreads();
    }
    #undef STAGE

    // C/D layout (verified m89/m91): col = lane&15, row = (lane>>4)*4 + reg.
    const int lr = (l >> 4) * 4;
    #pragma unroll
    for (int m = 0; m < 2; ++m) {
        #pragma unroll
        for (int n = 0; n < 2; ++n) {
            const int col = n0 + wc * 32 + n * 16 + la;
            const float bv = biasd[col];
            #pragma unroll
            for (int j = 0; j < 4; ++j) {
                const int row = m0 + wr * 32 + m * 16 + lr + j;
                hOut[(size_t)row * F_MID + col] = f2bf(fmaxf(accE[m][n][j], 0.f));
                out[(size_t)row * F_OUT + col]  = accW[m][n][j] + bv;
            }
        }
    }
}

// GEMM-B: out += h @ W_R^T  (R6 mode-2 core, standalone, XCD swizzle).
__global__ __launch_bounds__(256)
void k_gemmB(const ushort* __restrict__ x2,   // h = x2 + F_IN
             const ushort* __restrict__ Wbf,
             float* __restrict__ out)
{
    constexpr int BK = 64, NT = 16;
    __shared__ ushort lds[2][2][64 * 64];
    const int tid = threadIdx.x;
    const int w = tid >> 6, l = tid & 63;
    const int wr = w >> 1, wc = w & 1;
    const int la = l & 15;

    const int blk = blockIdx.x;
    const int sw  = (blk & 7) * 64 + (blk >> 3);
    const int m0  = (sw >> 4) * 64;
    const int n0  = (sw & 15) * 64;

    const ushort* A  = x2 + F_IN;
    const ushort* Bm = Wbf + F_IN;

    const int srow = w * 8 + (l >> 3);
    const int ldst = w * 512 + l * 8;

    f32x4 acc[2][2] = {};

    #define STAGE(buf, k0)                                                      \
        _Pragma("unroll")                                                       \
        for (int i = 0; i < 2; ++i) {                                           \
            int row = i * 32 + srow;                                            \
            int scol = (k0) + ((((l & 7) ^ (row & 7))) << 3);                   \
            gload16(A  + (size_t)(m0 + row) * F_MID + scol,                     \
                    &lds[buf][0][i * 2048 + ldst]);                             \
            gload16(Bm + (size_t)(n0 + row) * F_MID + scol,                     \
                    &lds[buf][1][i * 2048 + ldst]);                             \
        }

    STAGE(0, 0);
    __syncthreads();

    for (int t = 0; t < NT; ++t) {
        const int cur = t & 1;
        if (t + 1 < NT) STAGE(cur ^ 1, (t + 1) * BK);

        const ushort* sA = &lds[cur][0][0];
        const ushort* sB = &lds[cur][1][0];
        #pragma unroll
        for (int ks = 0; ks < 2; ++ks) {
            const int k8 = ks * 4 + (l >> 4);
            bf16x8 af[2], bg[2];
            #pragma unroll
            for (int m = 0; m < 2; ++m) {
                int row = wr * 32 + m * 16 + la;
                af[m] = *(const bf16x8*)(sA + row * BK + ((k8 ^ (row & 7)) << 3));
            }
            #pragma unroll
            for (int n = 0; n < 2; ++n) {
                int row = wc * 32 + n * 16 + la;
                bg[n] = *(const bf16x8*)(sB + row * BK + ((k8 ^ (row & 7)) << 3));
            }
            #pragma unroll
            for (int m = 0; m < 2; ++m)
                #pragma unroll
                for (int n = 0; n < 2; ++n)
                    acc[m][n] = __builtin_amdgcn_mfma_f32_16x16x32_bf16(
                        af[m], bg[n], acc[m][n], 0, 0, 0);
        }
        __syncthreads();
    }
    #undef STAGE

    const int lr = (l >> 4) * 4;
    #pragma unroll
    for (int m = 0; m < 2; ++m) {
        #pragma unroll
        for (int n = 0; n < 2; ++n) {
            const int col = n0 + wc * 32 + n * 16 + la;
            #pragma unroll
            for (int j = 0; j < 4; ++j) {
                const int row = m0 + wr * 32 + m * 16 + lr + j;
                out[(size_t)row * F_OUT + col] += acc[m][n][j];
            }
        }
    }
}

extern "C" void kernel_launch(void* const* d_in, const int* in_sizes, int n_in,
                              void* d_out, int out_size, void* d_ws, size_t ws_size,
                              hipStream_t stream) {
    const float* x          = (const float*)d_in[0];
    const int*   embed_rows = (const int*)  d_in[1];
    const int*   embed_cols = (const int*)  d_in[2];
    const float* embed_vals = (const float*)d_in[3];
    const int*   w_rows     = (const int*)  d_in[4];
    const int*   w_cols     = (const int*)  d_in[5];
    const float* w_vals     = (const float*)d_in[6];
    const int*   bias_idx   = (const int*)  d_in[7];
    const float* bias_vals  = (const float*)d_in[8];
    float* out = (float*)d_out;

    // Workspace layout (~26 MB):
    //   [0, 8M)          x2 bf16 [2048][2048]  (left = x, right = relu h)
    //   [8M, 16M)        W_f32 [1024][2048]
    //   [16M, 20M)       E_f32 [1024][1024]
    //   [20M, 20M+4K)    bias f32 [1024]
    //   [20M+4K, 22M+4K) E_bf16 [1024][1024]
    //   [22M+4K, 26M+4K) W_bf16 [1024][2048]
    // (R10 lesson: a barrier word placed at 26M sat INSIDE Wbf's last page and
    //  was clobbered by cvt -> 5.3 s of bounded-spin timeouts. Persistent-kernel
    //  fusion abandoned; back to stream-ordered launches.)
    char* ws = (char*)d_ws;
    ushort* x2    = (ushort*)ws;
    float*  Wf    = (float*)(ws + (8u << 20));
    float*  Ef    = (float*)(ws + (16u << 20));
    float*  biasd = (float*)(ws + (20u << 20));
    ushort* Ebf   = (ushort*)(ws + (20u << 20) + 4096);
    ushort* Wbf   = (ushort*)(ws + (22u << 20) + 4096);

    // 1. zero Wf | Ef | bias (12 MB + 4 KB = 786688 float4).
    k_zero4<<<3073, 256, 0, stream>>>((float4*)(ws + (8u << 20)), 786688);

    // 2. densify all sparse inputs (one launch)
    k_scatter_fused<<<NNZ_E / 256 + NNZ_W / 256 + 1, 256, 0, stream>>>(
        embed_rows, embed_cols, embed_vals,
        w_rows, w_cols, w_vals,
        bias_idx, bias_vals, Ef, Wf, biasd);

    // 3. all f32 -> bf16 conversions (one launch)
    k_cvt_fused<<<5120, 256, 0, stream>>>((const float4*)x, x2,
                                          (const float4*)Ef, Ebf,
                                          (const float4*)Wf, Wbf);

    // 4. GEMM-A': dual-B fused  {h = relu(x @ E^T)} + {out = x @ W_L^T + bias}
    //    512 blocks, one A-stage feeds both products.
    k_gemmA<<<512, 256, 0, stream>>>(x2, Ebf, Wbf, biasd, out, x2 + F_IN);

    // 5. GEMM-B: out += h @ W_R^T   (512 blocks)
    k_gemmB<<<512, 256, 0, stream>>>(x2, Wbf, out);
}